// Round 7
// baseline (245.023 us; speedup 1.0000x reference)
//
#include <hip/hip_runtime.h>

// VanillaMHA: B=4 T=2048 D=1024 H=16 DH=64. Inputs/output fp32; internal bf16
// MFMA pipeline w/ fp32 accumulation.
// R14: 8-phase-style deep-pipelined gemm0 (T3+T4 proper), ISOLATED change.
//  - gemm256q: 256x256 tile, BK=64, 512 thr (8 waves 2Mx4N, 128x64/wave),
//    LDS 128KB = dbuf x 2 half-tiles(128 rows) x {A,B}. 4 phases per K-tile,
//    each phase = {ds_read subtile | stage ONE half-tile | barrier |
//    lgkmcnt(0) | 16 MFMA | barrier}. B-halves prefetch 1 tile ahead (other
//    buffer, always safe); A-halves prefetch 2 tiles ahead into the SAME
//    buffer but only at phases 2/3, after all A-reads of the current tile
//    are barrier-fenced (audited: no timing race, unlike R11). Tile-boundary
//    s_waitcnt vmcnt(4) keeps 2 half-tiles in flight across barriers (never
//    drains to 0 except the last 2 tiles). Grid 32x12=384.
//  - gemm1 stays gemm128<1>; attn/prep/vtr unchanged from R13.
// Carried from R13: fused prep_k; attn with dedicated P buffer.
// Carried from R10: 8-wave attn blocks, padded stride-68 P rows, transposed
// QK^T (S^T = mfma(K,Q)), fq-axis l-reduce, setprio around MFMA.
// Carried from R8/R7: uniform-work attn pairing (qt,15-qt), XCD bid scramble,
// exp2-domain fixed-max softmax (log2e folded into Q), XOR-swizzled staging.

typedef __attribute__((ext_vector_type(8))) short bf8v;   // 8 x bf16 (4 VGPRs)
typedef __attribute__((ext_vector_type(4))) float f4v;    // 4 x fp32

#define Tt  2048
#define Dd  1024
#define Hh  16
#define DHh 64

#if __has_builtin(__builtin_amdgcn_exp2f)
#define EXP2(x) __builtin_amdgcn_exp2f(x)
#else
#define EXP2(x) __expf((x) * 0.69314718056f)
#endif

__device__ __forceinline__ ushort f2bf(float f) {
  union { float f; unsigned v; } c; c.f = f;
  unsigned r = c.v + 0x7fffu + ((c.v >> 16) & 1u);   // RNE
  return (ushort)(r >> 16);
}
__device__ __forceinline__ ushort f2bf_rn(float f) {  // cheap round-to-nearest
  union { float f; unsigned v; } c; c.f = f;
  return (ushort)((c.v + 0x8000u) >> 16);
}
__device__ __forceinline__ f4v zero4() { f4v z; z[0]=z[1]=z[2]=z[3]=0.f; return z; }

// async global->LDS, 16B/lane; LDS base wave-uniform, data lands at
// base + laneid*16. Global address is per-lane (exploited for the swizzle).
__device__ __forceinline__ void gl_lds16(const ushort* g, ushort* l) {
  __builtin_amdgcn_global_load_lds(
      (const __attribute__((address_space(1))) unsigned*)g,
      (__attribute__((address_space(3))) unsigned*)l, 16, 0, 0);
}

// ------------------------------------ fused preprocessing (cvt x2 + LayerNorm)
// blocks [0,3072):  wqkv f32 -> bf16
// blocks [3072,4096): wo f32 -> bf16
// blocks [4096,12288): LayerNorm row (bid-4096) -> bf16
__global__ __launch_bounds__(256)
void prep_k(const float* __restrict__ wqkv, ushort* __restrict__ wqkb,
            const float* __restrict__ wo,   ushort* __restrict__ wob,
            const float* __restrict__ x, const float* __restrict__ g,
            const float* __restrict__ bta, ushort* __restrict__ xn) {
  const int bid = blockIdx.x, tid = threadIdx.x;
  if (bid < 4096) {
    const float4* src = (bid < 3072) ? (const float4*)wqkv : (const float4*)wo;
    ushort4* dst      = (bid < 3072) ? (ushort4*)wqkb : (ushort4*)wob;
    const int i = ((bid < 3072) ? bid : (bid - 3072)) * 256 + tid;
    const float4 v = src[i];
    ushort4 o;
    o.x = f2bf(v.x); o.y = f2bf(v.y); o.z = f2bf(v.z); o.w = f2bf(v.w);
    dst[i] = o;
    return;
  }
  const int row = bid - 4096;
  const float4 v = ((const float4*)(x + row * Dd))[tid];
  float s  = v.x + v.y + v.z + v.w;
  float sq = v.x*v.x + v.y*v.y + v.z*v.z + v.w*v.w;
  #pragma unroll
  for (int off = 32; off; off >>= 1) {
    s  += __shfl_down(s,  off, 64);
    sq += __shfl_down(sq, off, 64);
  }
  __shared__ float red[8];
  const int w = tid >> 6, l = tid & 63;
  if (l == 0) { red[w] = s; red[w + 4] = sq; }
  __syncthreads();
  s  = red[0] + red[1] + red[2] + red[3];
  sq = red[4] + red[5] + red[6] + red[7];
  const float mu  = s * (1.0f / Dd);
  const float var = sq * (1.0f / Dd) - mu * mu;
  const float rs  = rsqrtf(var + 1e-5f);
  const float4 gv = ((const float4*)g)[tid];
  const float4 bv = ((const float4*)bta)[tid];
  ushort4 o;
  o.x = f2bf((v.x - mu) * rs * gv.x + bv.x);
  o.y = f2bf((v.y - mu) * rs * gv.y + bv.y);
  o.z = f2bf((v.z - mu) * rs * gv.z + bv.z);
  o.w = f2bf((v.w - mu) * rs * gv.w + bv.w);
  ((ushort4*)(xn + row * Dd))[tid] = o;
}

// ------------------------- deep-pipelined 256x256 QKV GEMM (Q/K/V scatter)
// 512 thr = 8 waves (2M x 4N); per-wave output 128x64 (acc[8][4]).
// LDS: As[buf][half][128x64], Bs likewise = 128 KB. Per K-tile 4 phases:
//  p0: read A-q0(8xb128)+B-n01(4); stage B0(t+1);            mfma m0-3 x n0-1
//  p1: read A-q1(8)+B-n23(4);      stage B1(t+1);            mfma m0-3 x n2-3
//  p2: re-read B-n01(4);           stage A0(t+2) [same buf]; mfma m4-7 x n0-1
//  p3:                             stage A1(t+2) [same buf]; mfma m4-7 x n2-3
//      + tile-boundary s_waitcnt vmcnt(4) (A(t+2) stays in flight).
// Same-buf A staging is safe: ALL A-reads of tile t issue by p1-top and are
// fenced by p1's lgkmcnt(0) + end-barrier before any wave reaches p2.
__global__ __launch_bounds__(512, 2)
void gemm256q(const ushort* __restrict__ A, const ushort* __restrict__ Bt,
              ushort* __restrict__ Oq, ushort* __restrict__ Ok,
              ushort* __restrict__ Ov, int Kd, int nbm) {
  __shared__ ushort As[2][2][128 * 64];   // 64 KB
  __shared__ ushort Bs[2][2][128 * 64];   // 64 KB
  const int tid = threadIdx.x;
  const int l = tid & 63, w = tid >> 6, fr = l & 15, fq = l >> 4;
  const int wm = w & 1, wn = w >> 1;                    // 2M x 4N wave grid
  const int bm = blockIdx.x % nbm, bn = blockIdx.x / nbm;
  const int gr8 = l >> 3, gc8s = ((l & 7) ^ gr8) * 8;   // swizzled 16B source col
  const int sw = fr & 7;
  const int cA = (fq ^ sw) * 8, cB = ((4 + fq) ^ sw) * 8;
  const int NIT = Kd >> 6;                              // 16

  f4v acc[8][4];
  #pragma unroll
  for (int m = 0; m < 8; m++)
    #pragma unroll
    for (int n = 0; n < 4; n++) acc[m][n] = zero4();

  // one half-tile = 128 rows x 64 k = 2 gl_lds calls (each call: 8 waves x
  // 8 rows; LDS dest wave-uniform, global src pre-swizzled).
  auto stageA = [&](int t, int half) {
    const int k0 = t * 64;
    ushort* dst = &As[t & 1][half][0];
    const int r0 = bm * 256 + half * 128;
    #pragma unroll
    for (int i = 0; i < 2; i++) {
      const int r = i * 64 + w * 8;
      gl_lds16(A + (r0 + r + gr8) * Kd + k0 + gc8s, dst + r * 64);
    }
  };
  auto stageB = [&](int t, int half) {
    const int k0 = t * 64;
    ushort* dst = &Bs[t & 1][half][0];
    const int r0 = bn * 256 + half * 128;
    #pragma unroll
    for (int i = 0; i < 2; i++) {
      const int r = i * 64 + w * 8;
      gl_lds16(Bt + (r0 + r + gr8) * Kd + k0 + gc8s, dst + r * 64);
    }
  };

  // prologue: tile0 fully + A(1); allow A(1)'s 4 loads to stay in flight.
  stageA(0, 0); stageA(0, 1); stageB(0, 0); stageB(0, 1);
  stageA(1, 0); stageA(1, 1);
  asm volatile("s_waitcnt vmcnt(4)" ::: "memory");
  __builtin_amdgcn_sched_barrier(0);
  __builtin_amdgcn_s_barrier();
  __builtin_amdgcn_sched_barrier(0);

  for (int t = 0; t < NIT; ++t) {
    const ushort* Ab = &As[t & 1][wm][0];
    const ushort* Bb = &Bs[t & 1][wn >> 1][(wn & 1) * (64 * 64)];
    bf8v a0[4][2], a1[4][2], b0[2][2], b1[2][2];

    // ---- phase 0 -------------------------------------------------------
    #pragma unroll
    for (int mi = 0; mi < 4; mi++) {
      a0[mi][0] = *(const bf8v*)&Ab[(mi * 16 + fr) * 64 + cA];
      a0[mi][1] = *(const bf8v*)&Ab[(mi * 16 + fr) * 64 + cB];
    }
    #pragma unroll
    for (int ni = 0; ni < 2; ni++) {
      b0[ni][0] = *(const bf8v*)&Bb[(ni * 16 + fr) * 64 + cA];
      b0[ni][1] = *(const bf8v*)&Bb[(ni * 16 + fr) * 64 + cB];
    }
    if (t + 1 < NIT) stageB(t + 1, 0);
    __builtin_amdgcn_s_barrier();
    asm volatile("s_waitcnt lgkmcnt(0)" ::: "memory");
    __builtin_amdgcn_sched_barrier(0);
    __builtin_amdgcn_s_setprio(1);
    #pragma unroll
    for (int mi = 0; mi < 4; mi++)
      #pragma unroll
      for (int ni = 0; ni < 2; ni++) {
        acc[mi][ni] = __builtin_amdgcn_mfma_f32_16x16x32_bf16(a0[mi][0], b0[ni][0], acc[mi][ni], 0, 0, 0);
        acc[mi][ni] = __builtin_amdgcn_mfma_f32_16x16x32_bf16(a0[mi][1], b0[ni][1], acc[mi][ni], 0, 0, 0);
      }
    __builtin_amdgcn_s_setprio(0);
    __builtin_amdgcn_s_barrier();

    // ---- phase 1 -------------------------------------------------------
    #pragma unroll
    for (int mi = 0; mi < 4; mi++) {
      a1[mi][0] = *(const bf8v*)&Ab[((4 + mi) * 16 + fr) * 64 + cA];
      a1[mi][1] = *(const bf8v*)&Ab[((4 + mi) * 16 + fr) * 64 + cB];
    }
    #pragma unroll
    for (int ni = 0; ni < 2; ni++) {
      b1[ni][0] = *(const bf8v*)&Bb[((2 + ni) * 16 + fr) * 64 + cA];
      b1[ni][1] = *(const bf8v*)&Bb[((2 + ni) * 16 + fr) * 64 + cB];
    }
    if (t + 1 < NIT) stageB(t + 1, 1);
    __builtin_amdgcn_s_barrier();
    asm volatile("s_waitcnt lgkmcnt(0)" ::: "memory");
    __builtin_amdgcn_sched_barrier(0);
    __builtin_amdgcn_s_setprio(1);
    #pragma unroll
    for (int mi = 0; mi < 4; mi++)
      #pragma unroll
      for (int ni = 0; ni < 2; ni++) {
        acc[mi][2 + ni] = __builtin_amdgcn_mfma_f32_16x16x32_bf16(a0[mi][0], b1[ni][0], acc[mi][2 + ni], 0, 0, 0);
        acc[mi][2 + ni] = __builtin_amdgcn_mfma_f32_16x16x32_bf16(a0[mi][1], b1[ni][1], acc[mi][2 + ni], 0, 0, 0);
      }
    __builtin_amdgcn_s_setprio(0);
    __builtin_amdgcn_s_barrier();

    // ---- phase 2 (all A-reads of tile t fenced by p1 barrier) ----------
    #pragma unroll
    for (int ni = 0; ni < 2; ni++) {
      b0[ni][0] = *(const bf8v*)&Bb[(ni * 16 + fr) * 64 + cA];
      b0[ni][1] = *(const bf8v*)&Bb[(ni * 16 + fr) * 64 + cB];
    }
    if (t + 2 < NIT) stageA(t + 2, 0);
    __builtin_amdgcn_s_barrier();
    asm volatile("s_waitcnt lgkmcnt(0)" ::: "memory");
    __builtin_amdgcn_sched_barrier(0);
    __builtin_amdgcn_s_setprio(1);
    #pragma unroll
    for (int mi = 0; mi < 4; mi++)
      #pragma unroll
      for (int ni = 0; ni < 2; ni++) {
        acc[4 + mi][ni] = __builtin_amdgcn_mfma_f32_16x16x32_bf16(a1[mi][0], b0[ni][0], acc[4 + mi][ni], 0, 0, 0);
        acc[4 + mi][ni] = __builtin_amdgcn_mfma_f32_16x16x32_bf16(a1[mi][1], b0[ni][1], acc[4 + mi][ni], 0, 0, 0);
      }
    __builtin_amdgcn_s_setprio(0);
    __builtin_amdgcn_s_barrier();

    // ---- phase 3 -------------------------------------------------------
    if (t + 2 < NIT) stageA(t + 2, 1);
    __builtin_amdgcn_s_barrier();
    __builtin_amdgcn_s_setprio(1);
    #pragma unroll
    for (int mi = 0; mi < 4; mi++)
      #pragma unroll
      for (int ni = 0; ni < 2; ni++) {
        acc[4 + mi][2 + ni] = __builtin_amdgcn_mfma_f32_16x16x32_bf16(a1[mi][0], b1[ni][0], acc[4 + mi][2 + ni], 0, 0, 0);
        acc[4 + mi][2 + ni] = __builtin_amdgcn_mfma_f32_16x16x32_bf16(a1[mi][1], b1[ni][1], acc[4 + mi][2 + ni], 0, 0, 0);
      }
    __builtin_amdgcn_s_setprio(0);
    // tile-boundary counted wait: force A(t+1),B(t+1) landed; keep A(t+2)'s
    // 4 loads in flight. Tail (last 2 tiles): drain.
    if (t + 2 < NIT) asm volatile("s_waitcnt vmcnt(4)" ::: "memory");
    else             asm volatile("s_waitcnt vmcnt(0)" ::: "memory");
    __builtin_amdgcn_sched_barrier(0);
    __builtin_amdgcn_s_barrier();
    __builtin_amdgcn_sched_barrier(0);
  }

  // epilogue: QKV scatter (Q scaled into exp2 domain)
  #pragma unroll
  for (int mi = 0; mi < 8; mi++) {
    const int grow = bm * 256 + wm * 128 + mi * 16 + fq * 4;   // + r
    #pragma unroll
    for (int ni = 0; ni < 4; ni++) {
      const int e = bn * 256 + wn * 64 + ni * 16 + fr;
      const int h = e / 192, inner = e % 192;
      const int sel = inner >> 6, dh = inner & 63;
      ushort* dst = (sel == 0) ? Oq : (sel == 1) ? Ok : Ov;
      #pragma unroll
      for (int r = 0; r < 4; r++) {
        const int row = grow + r;
        const int bb = row >> 11, tt = row & 2047;
        float v = acc[mi][ni][r];
        if (sel == 0) v *= 0.18033688f;            // (1/sqrt(64)) * log2(e)
        dst[((bb * Hh + h) * Tt + tt) * DHh + dh] = f2bf(v);
      }
    }
  }
}

// --------------------------------------- 128x128 GEMM  C = A * Bt^T (bf16)
// (gemm1 / out-projection only.) Pipelined: dbuf LDS, one barrier/iter.
template<int MODE>
__global__ __launch_bounds__(256)
void gemm128(const ushort* __restrict__ A, const ushort* __restrict__ Bt,
             void* __restrict__ O0v, ushort* __restrict__ O1, ushort* __restrict__ O2,
             int Kd, int nbm) {
  __shared__ ushort As[2][128 * 64], Bs[2][128 * 64];   // 64 KB
  const int tid = threadIdx.x;
  const int l = tid & 63, w = tid >> 6, fr = l & 15, fq = l >> 4;
  const int wm = w & 1, wn = w >> 1;
  const int bm = blockIdx.x % nbm, bn = blockIdx.x / nbm;
  const int gr8 = l >> 3, gc8s = ((l & 7) ^ gr8) * 8;   // swizzled 16B source col
  const int sw = fr & 7;
  const int cA = (fq ^ sw) * 8, cB = ((4 + fq) ^ sw) * 8;
  const int NIT = Kd >> 6;

  f4v acc[4][4];
  #pragma unroll
  for (int m = 0; m < 4; m++)
    #pragma unroll
    for (int n = 0; n < 4; n++) acc[m][n] = zero4();

  auto stage = [&](int it, int bi) {
    const int k0 = it * 64;
    #pragma unroll
    for (int i = 0; i < 4; i++) {
      const int row = w * 32 + i * 8;
      gl_lds16(A  + (bm * 128 + row + gr8) * Kd + k0 + gc8s, &As[bi][row * 64]);
      gl_lds16(Bt + (bn * 128 + row + gr8) * Kd + k0 + gc8s, &Bs[bi][row * 64]);
    }
  };

  stage(0, 0);
  for (int it = 0; it < NIT; ++it) {
    __syncthreads();                 // waits stage(it) (in flight during it-1's
                                     // compute) + guards buf[nxt] overwrite
    if (it + 1 < NIT) stage(it + 1, (it + 1) & 1);
    const ushort* Ab = As[it & 1];
    const ushort* Bb = Bs[it & 1];
    #pragma unroll
    for (int kk = 0; kk < 2; kk++) {
      const int cs = kk ? cB : cA;
      bf8v af[4], bf[4];
      #pragma unroll
      for (int m = 0; m < 4; m++)
        af[m] = *(const bf8v*)&Ab[(wm * 64 + m * 16 + fr) * 64 + cs];
      #pragma unroll
      for (int n = 0; n < 4; n++)
        bf[n] = *(const bf8v*)&Bb[(wn * 64 + n * 16 + fr) * 64 + cs];
      #pragma unroll
      for (int m = 0; m < 4; m++)
        #pragma unroll
        for (int n = 0; n < 4; n++)
          acc[m][n] = __builtin_amdgcn_mfma_f32_16x16x32_bf16(af[m], bf[n], acc[m][n], 0, 0, 0);
    }
  }

  #pragma unroll
  for (int m = 0; m < 4; m++) {
    const int grow = bm * 128 + wm * 64 + m * 16 + fq * 4;   // + r
    #pragma unroll
    for (int n = 0; n < 4; n++) {
      const int e = bn * 128 + wn * 64 + n * 16 + fr;
      #pragma unroll
      for (int r = 0; r < 4; r++) {
        const int row = grow + r;
        if (MODE == 0) {
          const int h = e / 192, inner = e % 192;
          const int sel = inner >> 6, dh = inner & 63;
          const int bb = row >> 11, t = row & 2047;
          float v = acc[m][n][r];
          if (sel == 0) v *= 0.18033688f;          // (1/sqrt(64)) * log2(e)
          ushort* dst = (sel == 0) ? (ushort*)O0v : (sel == 1) ? O1 : O2;
          dst[((bb * Hh + h) * Tt + t) * DHh + dh] = f2bf(v);
        } else {
          ((float*)O0v)[row * Dd + e] = acc[m][n][r];
        }
      }
    }
  }
}

// ---------------------------------------------- V transpose (b,h,t,dh)->(b,h,dh,t)
__global__ __launch_bounds__(256)
void vtr_k(const ushort* __restrict__ Vb, ushort* __restrict__ Vtg) {
  __shared__ ushort tile[64 * 72];
  const int tid = threadIdx.x;
  const int tt = blockIdx.x & 31;
  const int hb = blockIdx.x >> 5;
  const int base = hb * Tt * DHh;
  const int srow = tid >> 3, soff = (tid & 7) * 8;
  #pragma unroll
  for (int i = 0; i < 2; i++) {
    const int t = srow + i * 32;
    const uint4 vv = *(const uint4*)(Vb + base + (tt * 64 + t) * DHh + soff);
    const ushort* e = (const ushort*)&vv;
    #pragma unroll
    for (int j = 0; j < 8; j++) tile[(soff + j) * 72 + t] = e[j];
  }
  __syncthreads();
  #pragma unroll
  for (int i = 0; i < 2; i++) {
    const int dh = srow + i * 32;
    *(uint4*)(Vtg + base + dh * Tt + tt * 64 + soff) = *(const uint4*)&tile[dh * 72 + soff];
  }
}

// ------------------------------------------------------ flash attention
// R12 structure: 512 thr = 8 waves; one (b,h) + the q-tile PAIR (qt, 15-qt)
// processed sequentially -> uniform work; grid 512 = 2 blocks/CU = 16
// waves/CU. Wave w owns q-rows w*16..+15. Double-buffered Ks/Vt, single-
// barrier pipelined k-loop. Fixed-max exp2-domain softmax (Q pre-scaled by
// 0.125*log2e). Transposed QK^T: scT = mfma(K,Q) -> lane (fq,fr) has P for
// q-row fr at k = 16*nt+4*fq+{0..3} -> packed 8B P-stores into padded
// stride-68 rows of a DEDICATED P buffer. K/V/Q staging XOR-swizzled.
__global__ __launch_bounds__(512)
void attn_k(const ushort* __restrict__ Qb, const ushort* __restrict__ Kb,
            const ushort* __restrict__ Vtg, ushort* __restrict__ ctx) {
  __shared__ ushort QS[128 * 64];                    // 16 KB: Q staging (stride 64)
  __shared__ ushort Pb[128 * 68];                    // 17 KB: P (stride 68)
  __shared__ ushort Ks[2][64 * 64], Vt[2][64 * 64];  // 16 KB each (dbuf)
  const int tid = threadIdx.x;
  const int l = tid & 63, w = tid >> 6, fr = l & 15, fq = l >> 4;
  const int bid = blockIdx.x;
  // XCD scramble: blocks of one head share bid&7 -> same XCD under
  // round-robin dispatch; per-XCD KV working set = 8 heads ~= 4MB ~= L2.
  const int hb = (bid & 7) * 8 + (bid >> 6);       // b*16+h
  const int u  = (bid >> 3) & 7;                   // pair index 0..7
  const int h  = hb & 15, b = hb >> 4;
  const int headbase = hb * Tt * DHh;
  const int gr8 = l >> 3, gc8s = ((l & 7) ^ gr8) * 8;
  const int sw = fr & 7;
  const int cA = (fq ^ sw) * 8, cB = ((4 + fq) ^ sw) * 8;

  auto stageKV = [&](int kt, int bi) {
    const int row = w * 8;                         // 8 waves x 8 rows = 64
    gl_lds16(Kb  + headbase + (kt * 64 + row + gr8) * DHh + gc8s, &Ks[bi][row * 64]);
    gl_lds16(Vtg + headbase + (row + gr8) * Tt + kt * 64 + gc8s, &Vt[bi][row * 64]);
  };

  for (int half = 0; half < 2; ++half) {
    const int qt = half ? (15 - u) : u;
    const int qrow0w = qt * 128 + w * 16;          // wave's first q-row

    // seam guard: full drain (vmcnt+lgkm+barrier) before re-staging Q/KV
    // over buffers still being read by other waves in the previous half.
    if (half) __syncthreads();

    #pragma unroll
    for (int i = 0; i < 2; i++) {
      const int row = w * 16 + i * 8;
      gl_lds16(Qb + headbase + (qt * 128 + row + gr8) * DHh + gc8s, &QS[row * 64]);
    }
    stageKV(0, 0);
    __syncthreads();                               // Q + tile0 visible

    bf8v aq[2];
    aq[0] = *(const bf8v*)&QS[(w * 16 + fr) * 64 + cA];
    aq[1] = *(const bf8v*)&QS[(w * 16 + fr) * 64 + cB];
    __asm__ __volatile__("" ::: "memory");

    f4v o[4];
    #pragma unroll
    for (int n = 0; n < 4; n++) o[n] = zero4();
    float lsum = 0.f;                              // per-lane: q-row fr

    const int ktmax = 2 * qt + 1;
    for (int kt = 0; kt <= ktmax; ++kt) {
      if (kt) __syncthreads();       // waits stage(kt) (flew during kt-1's
                                     // compute) + guards buf[nxt] overwrite
      if (kt < ktmax) stageKV(kt + 1, (kt + 1) & 1);
      const ushort* K_ = Ks[kt & 1];
      const ushort* V_ = Vt[kt & 1];

      if (kt * 64 <= qrow0w + 15) {                // wave-uniform causal skip
        // S'^T = K (Q*log2e/8)^T : lane (fq,fr) -> q-row fr, k = 16nt+4fq+r
        f4v scT[4];
        #pragma unroll
        for (int n = 0; n < 4; n++) scT[n] = zero4();
        __builtin_amdgcn_s_setprio(1);
        #pragma unroll
        for (int nt = 0; nt < 4; nt++) {
          const bf8v k0 = *(const bf8v*)&K_[(nt * 16 + fr) * 64 + cA];
          const bf8v k1 = *(const bf8v*)&K_[(nt * 16 + fr) * 64 + cB];
          scT[nt] = __builtin_amdgcn_mfma_f32_16x16x32_bf16(k0, aq[0], scT[nt], 0, 0, 0);
          scT[nt] = __builtin_amdgcn_mfma_f32_16x16x32_bf16(k1, aq[1], scT[nt], 0, 0, 0);
        }
        __builtin_amdgcn_s_setprio(0);

        if (kt * 64 + 63 > qrow0w) {               // diagonal tiles only
          const int q0 = qrow0w + fr;
          #pragma unroll
          for (int nt = 0; nt < 4; nt++) {
            const int kc0 = kt * 64 + nt * 16 + fq * 4;
            #pragma unroll
            for (int r = 0; r < 4; r++)
              if (kc0 + r > q0) scT[nt][r] = -1e30f;
          }
        }

        // P = exp2(s') -> packed 8B stores, padded stride-68 rows (own buf).
        {
          const int prow = w * 16 + fr;
          ushort* pbase = &Pb[prow * 68 + fq * 4];
          #pragma unroll
          for (int nt = 0; nt < 4; nt++) {
            const float p0 = EXP2(scT[nt][0]), p1 = EXP2(scT[nt][1]);
            const float p2 = EXP2(scT[nt][2]), p3 = EXP2(scT[nt][3]);
            ushort4 pk;
            pk.x = f2bf_rn(p0); pk.y = f2bf_rn(p1);
            pk.z = f2bf_rn(p2); pk.w = f2bf_rn(p3);
            *(ushort4*)(pbase + nt * 16) = pk;
            lsum += (p0 + p1) + (p2 + p3);
          }
        }

        __asm__ __volatile__("" ::: "memory");   // order per-wave P stores before loads

        // O += P V
        __builtin_amdgcn_s_setprio(1);
        #pragma unroll
        for (int s = 0; s < 2; s++) {
          const bf8v ap = *(const bf8v*)&Pb[(w * 16 + fr) * 68 + s * 32 + fq * 8];
          #pragma unroll
          for (int nt = 0; nt < 4; nt++) {
            const bf8v bv2 = *(const bf8v*)&V_[(nt * 16 + fr) * 64 + (s ? cB : cA)];
            o[nt] = __builtin_amdgcn_mfma_f32_16x16x32_bf16(ap, bv2, o[nt], 0, 0, 0);
          }
        }
        __builtin_amdgcn_s_setprio(0);
      }
    }

    // finalize l: reduce over fq groups (lanes xor 16,32 share q-row fr),
    // then broadcast to the lanes that own that q-row in the o-layout.
    float t = lsum;
    t += __shfl_xor(t, 16, 64);
    t += __shfl_xor(t, 32, 64);
    const float inv = 1.0f / t;
    #pragma unroll
    for (int r = 0; r < 4; r++) {
      // o[nt][r] belongs to q-row fq*4+r; its inv lives in lane 20*fq+r.
      const float iv = __shfl(inv, 20 * fq + r, 64);
      const int rowg = b * Tt + qt * 128 + w * 16 + fq * 4 + r;
      #pragma unroll
      for (int nt = 0; nt < 4; nt++)
        ctx[rowg * Dd + h * DHh + nt * 16 + fr] = f2bf(o[nt][r] * iv);
    }
  }
}

// ---------------------------------------------------------------- launcher
extern "C" void kernel_launch(void* const* d_in, const int* in_sizes, int n_in,
                              void* d_out, int out_size, void* d_ws, size_t ws_size,
                              hipStream_t stream) {
  const float* x    = (const float*)d_in[0];
  const float* g    = (const float*)d_in[1];
  const float* bta  = (const float*)d_in[2];
  const float* wqkv = (const float*)d_in[3];
  const float* wo   = (const float*)d_in[4];

  const int NROW = 4 * Tt;                 // 8192
  const int NQ   = 4 * Hh * Tt * DHh;      // 8388608
  ushort* xn   = (ushort*)d_ws;            // reused as VbT after gemm0
  ushort* Qb   = xn + NROW * Dd;
  ushort* Kb   = Qb + NQ;
  ushort* Vb   = Kb + NQ;
  ushort* ctx  = Vb + NQ;
  ushort* wqkb = ctx + NROW * Dd;
  ushort* wob  = wqkb + 3 * Dd * Dd;
  ushort* VbT  = xn;                       // xn dead after gemm0

  prep_k<<<3072 + 1024 + NROW, 256, 0, stream>>>(wqkv, wqkb, wo, wob, x, g, bta, xn);
  gemm256q<<<32 * 12, 512, 0, stream>>>(xn, wqkb, Qb, Kb, Vb, Dd, 32);
  vtr_k<<<4 * Hh * (Tt / 64), 256, 0, stream>>>(Vb, VbT);
  attn_k<<<4 * Hh * (Tt / 128) / 2, 512, 0, stream>>>(Qb, Kb, VbT, ctx);
  gemm128<1><<<64 * 8, 256, 0, stream>>>(ctx, wob, (void*)d_out, nullptr, nullptr, Dd, 64);
}

// Round 8
// 231.291 us; speedup vs baseline: 1.0594x; 1.0594x over previous
//
#include <hip/hip_runtime.h>

// VanillaMHA: B=4 T=2048 D=1024 H=16 DH=64. Inputs/output fp32; internal bf16
// MFMA pipeline w/ fp32 accumulation.
// R15: revert gemm0 to proven gemm128 (R14's 4-phase 256^2 regressed: 700 vs
// 763 TF — grid tail 384=1.5 rounds + 1 blk/CU barrier convoy; deep-pipeline
// prospecting closed at this K=1024 size). NEW: vtr_k ELIMINATED — gemm0's
// epilogue writes V directly transposed (b,h,dh,t) via a col-major LDS tile
// (aliased over As after a barrier): in a 128-wide bn tile the 64-col runs
// are sel-uniform (192=3*64) and run r maps onto waves wn==r, so the V-run's
// 2 waves stage acc -> LDS [64dh][140t], then all 8 waves write 16B-coalesced
// t-rows. Saves the vtr dispatch + 32MB HBM round-trip. V lands in the Vb
// workspace slot (no aliasing with gemm0 input).
// Carried from R13: fused prep_k; attn with dedicated P buffer.
// Carried from R10: 8-wave attn blocks, padded stride-68 P rows, transposed
// QK^T (S^T = mfma(K,Q)), fq-axis l-reduce, setprio around MFMA.
// Carried from R8/R7: uniform-work attn pairing (qt,15-qt), XCD bid scramble,
// exp2-domain fixed-max softmax (log2e folded into Q), XOR-swizzled staging.

typedef __attribute__((ext_vector_type(8))) short bf8v;   // 8 x bf16 (4 VGPRs)
typedef __attribute__((ext_vector_type(4))) float f4v;    // 4 x fp32

#define Tt  2048
#define Dd  1024
#define Hh  16
#define DHh 64

#if __has_builtin(__builtin_amdgcn_exp2f)
#define EXP2(x) __builtin_amdgcn_exp2f(x)
#else
#define EXP2(x) __expf((x) * 0.69314718056f)
#endif

__device__ __forceinline__ ushort f2bf(float f) {
  union { float f; unsigned v; } c; c.f = f;
  unsigned r = c.v + 0x7fffu + ((c.v >> 16) & 1u);   // RNE
  return (ushort)(r >> 16);
}
__device__ __forceinline__ ushort f2bf_rn(float f) {  // cheap round-to-nearest
  union { float f; unsigned v; } c; c.f = f;
  return (ushort)((c.v + 0x8000u) >> 16);
}
__device__ __forceinline__ f4v zero4() { f4v z; z[0]=z[1]=z[2]=z[3]=0.f; return z; }

// async global->LDS, 16B/lane; LDS base wave-uniform, data lands at
// base + laneid*16. Global address is per-lane (exploited for the swizzle).
__device__ __forceinline__ void gl_lds16(const ushort* g, ushort* l) {
  __builtin_amdgcn_global_load_lds(
      (const __attribute__((address_space(1))) unsigned*)g,
      (__attribute__((address_space(3))) unsigned*)l, 16, 0, 0);
}

// ------------------------------------ fused preprocessing (cvt x2 + LayerNorm)
// blocks [0,3072):  wqkv f32 -> bf16
// blocks [3072,4096): wo f32 -> bf16
// blocks [4096,12288): LayerNorm row (bid-4096) -> bf16
__global__ __launch_bounds__(256)
void prep_k(const float* __restrict__ wqkv, ushort* __restrict__ wqkb,
            const float* __restrict__ wo,   ushort* __restrict__ wob,
            const float* __restrict__ x, const float* __restrict__ g,
            const float* __restrict__ bta, ushort* __restrict__ xn) {
  const int bid = blockIdx.x, tid = threadIdx.x;
  if (bid < 4096) {
    const float4* src = (bid < 3072) ? (const float4*)wqkv : (const float4*)wo;
    ushort4* dst      = (bid < 3072) ? (ushort4*)wqkb : (ushort4*)wob;
    const int i = ((bid < 3072) ? bid : (bid - 3072)) * 256 + tid;
    const float4 v = src[i];
    ushort4 o;
    o.x = f2bf(v.x); o.y = f2bf(v.y); o.z = f2bf(v.z); o.w = f2bf(v.w);
    dst[i] = o;
    return;
  }
  const int row = bid - 4096;
  const float4 v = ((const float4*)(x + row * Dd))[tid];
  float s  = v.x + v.y + v.z + v.w;
  float sq = v.x*v.x + v.y*v.y + v.z*v.z + v.w*v.w;
  #pragma unroll
  for (int off = 32; off; off >>= 1) {
    s  += __shfl_down(s,  off, 64);
    sq += __shfl_down(sq, off, 64);
  }
  __shared__ float red[8];
  const int w = tid >> 6, l = tid & 63;
  if (l == 0) { red[w] = s; red[w + 4] = sq; }
  __syncthreads();
  s  = red[0] + red[1] + red[2] + red[3];
  sq = red[4] + red[5] + red[6] + red[7];
  const float mu  = s * (1.0f / Dd);
  const float var = sq * (1.0f / Dd) - mu * mu;
  const float rs  = rsqrtf(var + 1e-5f);
  const float4 gv = ((const float4*)g)[tid];
  const float4 bv = ((const float4*)bta)[tid];
  ushort4 o;
  o.x = f2bf((v.x - mu) * rs * gv.x + bv.x);
  o.y = f2bf((v.y - mu) * rs * gv.y + bv.y);
  o.z = f2bf((v.z - mu) * rs * gv.z + bv.z);
  o.w = f2bf((v.w - mu) * rs * gv.w + bv.w);
  ((ushort4*)(xn + row * Dd))[tid] = o;
}

// --------------------------------------- 128x128 GEMM  C = A * Bt^T (bf16)
// Pipelined: dbuf LDS, one barrier/iter, prefetch issued right after barrier.
// MODE 0: QKV projection. Q scaled by 0.125*log2(e); Q/K scattered direct
//         (b,h,t,dh); V written TRANSPOSED (b,h,dh,t) via LDS-staged
//         epilogue (see header comment). MODE 1: out proj -> f32 row-major.
template<int MODE>
__global__ __launch_bounds__(256)
void gemm128(const ushort* __restrict__ A, const ushort* __restrict__ Bt,
             void* __restrict__ O0v, ushort* __restrict__ O1, ushort* __restrict__ O2,
             int Kd, int nbm) {
  __shared__ ushort As[2][128 * 64], Bs[2][128 * 64];   // 64 KB
  const int tid = threadIdx.x;
  const int l = tid & 63, w = tid >> 6, fr = l & 15, fq = l >> 4;
  const int wm = w & 1, wn = w >> 1;
  const int bm = blockIdx.x % nbm, bn = blockIdx.x / nbm;
  const int gr8 = l >> 3, gc8s = ((l & 7) ^ gr8) * 8;   // swizzled 16B source col
  const int sw = fr & 7;
  const int cA = (fq ^ sw) * 8, cB = ((4 + fq) ^ sw) * 8;
  const int NIT = Kd >> 6;

  f4v acc[4][4];
  #pragma unroll
  for (int m = 0; m < 4; m++)
    #pragma unroll
    for (int n = 0; n < 4; n++) acc[m][n] = zero4();

  auto stage = [&](int it, int bi) {
    const int k0 = it * 64;
    #pragma unroll
    for (int i = 0; i < 4; i++) {
      const int row = w * 32 + i * 8;
      gl_lds16(A  + (bm * 128 + row + gr8) * Kd + k0 + gc8s, &As[bi][row * 64]);
      gl_lds16(Bt + (bn * 128 + row + gr8) * Kd + k0 + gc8s, &Bs[bi][row * 64]);
    }
  };

  stage(0, 0);
  for (int it = 0; it < NIT; ++it) {
    __syncthreads();                 // waits stage(it) (in flight during it-1's
                                     // compute) + guards buf[nxt] overwrite
    if (it + 1 < NIT) stage(it + 1, (it + 1) & 1);
    const ushort* Ab = As[it & 1];
    const ushort* Bb = Bs[it & 1];
    #pragma unroll
    for (int kk = 0; kk < 2; kk++) {
      const int cs = kk ? cB : cA;
      bf8v af[4], bf[4];
      #pragma unroll
      for (int m = 0; m < 4; m++)
        af[m] = *(const bf8v*)&Ab[(wm * 64 + m * 16 + fr) * 64 + cs];
      #pragma unroll
      for (int n = 0; n < 4; n++)
        bf[n] = *(const bf8v*)&Bb[(wn * 64 + n * 16 + fr) * 64 + cs];
      #pragma unroll
      for (int m = 0; m < 4; m++)
        #pragma unroll
        for (int n = 0; n < 4; n++)
          acc[m][n] = __builtin_amdgcn_mfma_f32_16x16x32_bf16(af[m], bf[n], acc[m][n], 0, 0, 0);
    }
  }

  // ---- direct epilogue: MODE1 full; MODE0 Q/K only (V staged below) ----
  #pragma unroll
  for (int m = 0; m < 4; m++) {
    const int grow = bm * 128 + wm * 64 + m * 16 + fq * 4;   // + r
    #pragma unroll
    for (int n = 0; n < 4; n++) {
      const int e = bn * 128 + wn * 64 + n * 16 + fr;
      #pragma unroll
      for (int r = 0; r < 4; r++) {
        const int row = grow + r;
        if (MODE == 0) {
          const int h = e / 192, inner = e % 192;
          const int sel = inner >> 6, dh = inner & 63;
          if (sel == 2) continue;                  // V goes via staged path
          const int bb = row >> 11, t = row & 2047;
          float v = acc[m][n][r];
          if (sel == 0) v *= 0.18033688f;          // (1/sqrt(64)) * log2(e)
          ushort* dst = (sel == 0) ? (ushort*)O0v : O1;
          dst[((bb * Hh + h) * Tt + t) * DHh + dh] = f2bf(v);
        } else {
          ((float*)O0v)[row * Dd + e] = acc[m][n][r];
        }
      }
    }
  }

  // ---- MODE0 staged-V epilogue: write V transposed (b,h,dh,t) ----------
  // In a 128-wide bn tile the two 64-col runs are sel-uniform; the V-run
  // (if any) maps onto waves wn==vrun. Those 2 waves stage acc into a
  // col-major LDS tile Vl[dh][140] (aliased over As after a barrier); all 8
  // waves then write 16B-coalesced t-rows.
  if (MODE == 0) {
    const int bnm3 = bn % 3;
    if (bnm3 != 0) {                               // block-uniform branch
      const int vrun = (bnm3 == 1) ? 0 : 1;
      ushort* Vl = &As[0][0];                      // 64*140 ushorts <= As
      __syncthreads();                             // main-loop LDS reads done
      if (wn == vrun) {
        #pragma unroll
        for (int m = 0; m < 4; m++) {
          const int row0 = wm * 64 + m * 16 + fq * 4;
          #pragma unroll
          for (int n = 0; n < 4; n++) {
            const int col = n * 16 + fr;           // = dh
            ushort4 pk;
            pk.x = f2bf(acc[m][n][0]); pk.y = f2bf(acc[m][n][1]);
            pk.z = f2bf(acc[m][n][2]); pk.w = f2bf(acc[m][n][3]);
            *(ushort4*)&Vl[col * 140 + row0] = pk;
          }
        }
      }
      __syncthreads();
      const int evr = bn * 128 + vrun * 64;
      const int hq  = evr / 192;
      const int bb  = bm >> 4, t0g = (bm & 15) * 128;
      ushort* vdst = O2 + (bb * Hh + hq) * (size_t)(DHh * Tt) + t0g;
      #pragma unroll
      for (int i = 0; i < 4; i++) {
        const int u = i * 256 + tid;               // 1024 units
        const int dh = u >> 4, tc = (u & 15) * 8;
        const ushort4 lo = *(const ushort4*)&Vl[dh * 140 + tc];
        const ushort4 hi = *(const ushort4*)&Vl[dh * 140 + tc + 4];
        union { ushort s[8]; uint4 v; } pk;
        pk.s[0] = lo.x; pk.s[1] = lo.y; pk.s[2] = lo.z; pk.s[3] = lo.w;
        pk.s[4] = hi.x; pk.s[5] = hi.y; pk.s[6] = hi.z; pk.s[7] = hi.w;
        *(uint4*)&vdst[dh * Tt + tc] = pk.v;
      }
    }
  }
}

// ------------------------------------------------------ flash attention
// R12 structure: 512 thr = 8 waves; one (b,h) + the q-tile PAIR (qt, 15-qt)
// processed sequentially -> uniform work; grid 512 = 2 blocks/CU = 16
// waves/CU. Wave w owns q-rows w*16..+15. Double-buffered Ks/Vt, single-
// barrier pipelined k-loop. Fixed-max exp2-domain softmax (Q pre-scaled by
// 0.125*log2e). Transposed QK^T: scT = mfma(K,Q) -> lane (fq,fr) has P for
// q-row fr at k = 16*nt+4*fq+{0..3} -> packed 8B P-stores into padded
// stride-68 rows of a DEDICATED P buffer. K/V/Q staging XOR-swizzled.
__global__ __launch_bounds__(512)
void attn_k(const ushort* __restrict__ Qb, const ushort* __restrict__ Kb,
            const ushort* __restrict__ Vtg, ushort* __restrict__ ctx) {
  __shared__ ushort QS[128 * 64];                    // 16 KB: Q staging (stride 64)
  __shared__ ushort Pb[128 * 68];                    // 17 KB: P (stride 68)
  __shared__ ushort Ks[2][64 * 64], Vt[2][64 * 64];  // 16 KB each (dbuf)
  const int tid = threadIdx.x;
  const int l = tid & 63, w = tid >> 6, fr = l & 15, fq = l >> 4;
  const int bid = blockIdx.x;
  // XCD scramble: blocks of one head share bid&7 -> same XCD under
  // round-robin dispatch; per-XCD KV working set = 8 heads ~= 4MB ~= L2.
  const int hb = (bid & 7) * 8 + (bid >> 6);       // b*16+h
  const int u  = (bid >> 3) & 7;                   // pair index 0..7
  const int h  = hb & 15, b = hb >> 4;
  const int headbase = hb * Tt * DHh;
  const int gr8 = l >> 3, gc8s = ((l & 7) ^ gr8) * 8;
  const int sw = fr & 7;
  const int cA = (fq ^ sw) * 8, cB = ((4 + fq) ^ sw) * 8;

  auto stageKV = [&](int kt, int bi) {
    const int row = w * 8;                         // 8 waves x 8 rows = 64
    gl_lds16(Kb  + headbase + (kt * 64 + row + gr8) * DHh + gc8s, &Ks[bi][row * 64]);
    gl_lds16(Vtg + headbase + (row + gr8) * Tt + kt * 64 + gc8s, &Vt[bi][row * 64]);
  };

  for (int half = 0; half < 2; ++half) {
    const int qt = half ? (15 - u) : u;
    const int qrow0w = qt * 128 + w * 16;          // wave's first q-row

    // seam guard: full drain (vmcnt+lgkm+barrier) before re-staging Q/KV
    // over buffers still being read by other waves in the previous half.
    if (half) __syncthreads();

    #pragma unroll
    for (int i = 0; i < 2; i++) {
      const int row = w * 16 + i * 8;
      gl_lds16(Qb + headbase + (qt * 128 + row + gr8) * DHh + gc8s, &QS[row * 64]);
    }
    stageKV(0, 0);
    __syncthreads();                               // Q + tile0 visible

    bf8v aq[2];
    aq[0] = *(const bf8v*)&QS[(w * 16 + fr) * 64 + cA];
    aq[1] = *(const bf8v*)&QS[(w * 16 + fr) * 64 + cB];
    __asm__ __volatile__("" ::: "memory");

    f4v o[4];
    #pragma unroll
    for (int n = 0; n < 4; n++) o[n] = zero4();
    float lsum = 0.f;                              // per-lane: q-row fr

    const int ktmax = 2 * qt + 1;
    for (int kt = 0; kt <= ktmax; ++kt) {
      if (kt) __syncthreads();       // waits stage(kt) (flew during kt-1's
                                     // compute) + guards buf[nxt] overwrite
      if (kt < ktmax) stageKV(kt + 1, (kt + 1) & 1);
      const ushort* K_ = Ks[kt & 1];
      const ushort* V_ = Vt[kt & 1];

      if (kt * 64 <= qrow0w + 15) {                // wave-uniform causal skip
        // S'^T = K (Q*log2e/8)^T : lane (fq,fr) -> q-row fr, k = 16nt+4fq+r
        f4v scT[4];
        #pragma unroll
        for (int n = 0; n < 4; n++) scT[n] = zero4();
        __builtin_amdgcn_s_setprio(1);
        #pragma unroll
        for (int nt = 0; nt < 4; nt++) {
          const bf8v k0 = *(const bf8v*)&K_[(nt * 16 + fr) * 64 + cA];
          const bf8v k1 = *(const bf8v*)&K_[(nt * 16 + fr) * 64 + cB];
          scT[nt] = __builtin_amdgcn_mfma_f32_16x16x32_bf16(k0, aq[0], scT[nt], 0, 0, 0);
          scT[nt] = __builtin_amdgcn_mfma_f32_16x16x32_bf16(k1, aq[1], scT[nt], 0, 0, 0);
        }
        __builtin_amdgcn_s_setprio(0);

        if (kt * 64 + 63 > qrow0w) {               // diagonal tiles only
          const int q0 = qrow0w + fr;
          #pragma unroll
          for (int nt = 0; nt < 4; nt++) {
            const int kc0 = kt * 64 + nt * 16 + fq * 4;
            #pragma unroll
            for (int r = 0; r < 4; r++)
              if (kc0 + r > q0) scT[nt][r] = -1e30f;
          }
        }

        // P = exp2(s') -> packed 8B stores, padded stride-68 rows (own buf).
        {
          const int prow = w * 16 + fr;
          ushort* pbase = &Pb[prow * 68 + fq * 4];
          #pragma unroll
          for (int nt = 0; nt < 4; nt++) {
            const float p0 = EXP2(scT[nt][0]), p1 = EXP2(scT[nt][1]);
            const float p2 = EXP2(scT[nt][2]), p3 = EXP2(scT[nt][3]);
            ushort4 pk;
            pk.x = f2bf_rn(p0); pk.y = f2bf_rn(p1);
            pk.z = f2bf_rn(p2); pk.w = f2bf_rn(p3);
            *(ushort4*)(pbase + nt * 16) = pk;
            lsum += (p0 + p1) + (p2 + p3);
          }
        }

        __asm__ __volatile__("" ::: "memory");   // order per-wave P stores before loads

        // O += P V
        __builtin_amdgcn_s_setprio(1);
        #pragma unroll
        for (int s = 0; s < 2; s++) {
          const bf8v ap = *(const bf8v*)&Pb[(w * 16 + fr) * 68 + s * 32 + fq * 8];
          #pragma unroll
          for (int nt = 0; nt < 4; nt++) {
            const bf8v bv2 = *(const bf8v*)&V_[(nt * 16 + fr) * 64 + (s ? cB : cA)];
            o[nt] = __builtin_amdgcn_mfma_f32_16x16x32_bf16(ap, bv2, o[nt], 0, 0, 0);
          }
        }
        __builtin_amdgcn_s_setprio(0);
      }
    }

    // finalize l: reduce over fq groups (lanes xor 16,32 share q-row fr),
    // then broadcast to the lanes that own that q-row in the o-layout.
    float t = lsum;
    t += __shfl_xor(t, 16, 64);
    t += __shfl_xor(t, 32, 64);
    const float inv = 1.0f / t;
    #pragma unroll
    for (int r = 0; r < 4; r++) {
      // o[nt][r] belongs to q-row fq*4+r; its inv lives in lane 20*fq+r.
      const float iv = __shfl(inv, 20 * fq + r, 64);
      const int rowg = b * Tt + qt * 128 + w * 16 + fq * 4 + r;
      #pragma unroll
      for (int nt = 0; nt < 4; nt++)
        ctx[rowg * Dd + h * DHh + nt * 16 + fr] = f2bf(o[nt][r] * iv);
    }
  }
}

// ---------------------------------------------------------------- launcher
extern "C" void kernel_launch(void* const* d_in, const int* in_sizes, int n_in,
                              void* d_out, int out_size, void* d_ws, size_t ws_size,
                              hipStream_t stream) {
  const float* x    = (const float*)d_in[0];
  const float* g    = (const float*)d_in[1];
  const float* bta  = (const float*)d_in[2];
  const float* wqkv = (const float*)d_in[3];
  const float* wo   = (const float*)d_in[4];

  const int NROW = 4 * Tt;                 // 8192
  const int NQ   = 4 * Hh * Tt * DHh;      // 8388608
  ushort* xn   = (ushort*)d_ws;
  ushort* Qb   = xn + NROW * Dd;
  ushort* Kb   = Qb + NQ;
  ushort* Vb   = Kb + NQ;                  // holds V TRANSPOSED (b,h,dh,t)
  ushort* ctx  = Vb + NQ;
  ushort* wqkb = ctx + NROW * Dd;
  ushort* wob  = wqkb + 3 * Dd * Dd;

  prep_k<<<3072 + 1024 + NROW, 256, 0, stream>>>(wqkv, wqkb, wo, wob, x, g, bta, xn);
  gemm128<0><<<64 * 24, 256, 0, stream>>>(xn, wqkb, Qb, Kb, Vb, Dd, 64);
  attn_k<<<4 * Hh * (Tt / 128) / 2, 512, 0, stream>>>(Qb, Kb, Vb, ctx);
  gemm128<1><<<64 * 8, 256, 0, stream>>>(ctx, wob, (void*)d_out, nullptr, nullptr, Dd, 64);
}